// Round 6
// baseline (529.030 us; speedup 1.0000x reference)
//
#include <hip/hip_runtime.h>
#include <hip/hip_bf16.h>
#include <math.h>

// Problem constants
#define NB 8
#define NS 4096
#define NL 77
#define NLP 80     // padded L for score tiles (5 x 16)
#define NLPV 96    // padded L for PV K-dim (3 x 32)
#define ND 1280
#define NC 2048
#define NH 20
#define NDH 64
#define QK_SCALE 0.125f

typedef __attribute__((ext_vector_type(4))) float f32x4;
typedef __attribute__((ext_vector_type(8))) short bf16x8;

static __device__ __forceinline__ void gload_lds16(const void* g, void* l) {
  __builtin_amdgcn_global_load_lds(
      (const __attribute__((address_space(1))) void*)g,
      (__attribute__((address_space(3))) void*)l, 16, 0, 0);
}

#define LGKM0() asm volatile("s_waitcnt lgkmcnt(0)" ::: "memory")

// ---------------- f32 -> bf16 convert (encoder states only) ----------------
__global__ void cvt_bf16_kern(const float* __restrict__ in,
                              __hip_bfloat16* __restrict__ out, long n)
{
  long i = ((long)blockIdx.x * blockDim.x + threadIdx.x) * 4;
  long stride = (long)gridDim.x * blockDim.x * 4;
  for (; i < n; i += stride) {
    float4 v = *reinterpret_cast<const float4*>(in + i);
    union { __hip_bfloat16 h[4]; ushort4 u; } r;
    r.h[0] = __float2bfloat16(v.x);
    r.h[1] = __float2bfloat16(v.y);
    r.h[2] = __float2bfloat16(v.z);
    r.h[3] = __float2bfloat16(v.w);
    *reinterpret_cast<ushort4*>(out + i) = r.u;
  }
}

// ------------- transpose f32 [rows][cols] -> bf16 [cols][rows] -------------
__global__ void transpose_bf16_kern(const float* __restrict__ in,
                                    __hip_bfloat16* __restrict__ out,
                                    int rows, int cols)
{
  __shared__ float t[32][33];
  int c0 = blockIdx.x * 32, r0 = blockIdx.y * 32;
  int tx = threadIdx.x, ty = threadIdx.y;
  for (int i = ty; i < 32; i += 8) {
    int r = r0 + i, c = c0 + tx;
    t[i][tx] = (r < rows && c < cols) ? in[(long)r * cols + c] : 0.f;
  }
  __syncthreads();
  for (int i = ty; i < 32; i += 8) {
    int oc = c0 + i, orr = r0 + tx;   // out[oc][orr] = in[orr][oc]
    if (oc < cols && orr < rows)
      out[(long)oc * rows + orr] = __float2bfloat16(t[tx][i]);
  }
}

// ---------------- small GEMM (KV proj): C[M][N] = A @ Bt^T, m97-style ----------------
__global__ __launch_bounds__(256)
void gemm_bt_kern(const __hip_bfloat16* __restrict__ A,
                  const __hip_bfloat16* __restrict__ Bt,
                  void* __restrict__ C, const float* __restrict__ bias,
                  int M, int N, int K, int mode)
{
  __shared__ __align__(16) __hip_bfloat16 As[128 * 32];
  __shared__ __align__(16) __hip_bfloat16 Bs[128 * 32];
  const int t = threadIdx.x;
  const int lane = t & 63;
  const int w = t >> 6;
  const int wm = w >> 1, wn = w & 1;     // 2x2 waves of 64x64
  const int lr = lane & 15, hi = lane >> 4, lk = hi * 8;
  const long m0 = (long)blockIdx.x * 128;
  const long n0 = (long)blockIdx.y * 128;

  f32x4 acc[4][4];
#pragma unroll
  for (int mi = 0; mi < 4; ++mi)
#pragma unroll
    for (int ni = 0; ni < 4; ++ni) acc[mi][ni] = {0.f, 0.f, 0.f, 0.f};

  for (int k0 = 0; k0 < K; k0 += 32) {
    __syncthreads();
#pragma unroll
    for (int rnd = 0; rnd < 2; ++rnd) {
      int idx = rnd * 256 + t;
      int row = idx >> 2, kpp = (idx & 3) * 8;
      long arow = m0 + row; if (arow >= M) arow = M - 1;
      gload_lds16(A + arow * K + k0 + kpp, (void*)(As + idx * 8));
      long brow = n0 + row;
      gload_lds16(Bt + brow * K + k0 + kpp, (void*)(Bs + idx * 8));
    }
    __syncthreads();

    bf16x8 af[4], bfr[4];
#pragma unroll
    for (int i = 0; i < 4; ++i) {
      af[i]  = *reinterpret_cast<const bf16x8*>(As + (wm * 64 + i * 16 + lr) * 32 + lk);
      bfr[i] = *reinterpret_cast<const bf16x8*>(Bs + (wn * 64 + i * 16 + lr) * 32 + lk);
    }
#pragma unroll
    for (int mi = 0; mi < 4; ++mi)
#pragma unroll
      for (int ni = 0; ni < 4; ++ni)
        acc[mi][ni] = __builtin_amdgcn_mfma_f32_16x16x32_bf16(af[mi], bfr[ni], acc[mi][ni], 0, 0, 0);
  }

#pragma unroll
  for (int mi = 0; mi < 4; ++mi) {
#pragma unroll
    for (int r = 0; r < 4; ++r) {
      long row = m0 + wm * 64 + mi * 16 + hi * 4 + r;
      if (row < M) {
#pragma unroll
        for (int ni = 0; ni < 4; ++ni) {
          long col = n0 + wn * 64 + ni * 16 + lr;
          if (mode == 0)
            ((__hip_bfloat16*)C)[row * N + col] = __float2bfloat16(acc[mi][ni][r]);
          else
            ((float*)C)[row * N + col] = acc[mi][ni][r] + bias[col];
        }
      }
    }
  }
}

// ---- big GEMM: 128x128 tile, BK=64, single-buffered LDS, max occupancy (m97 structure) ----
// AF32: A operand is f32 in global, staged raw and converted to bf16 at fragment read.
// Requires M%128==0, N%128==0, K%64==0, gridDim.x == (M/128)*(N/128), grid%8==0.
template<bool AF32>
__global__ __launch_bounds__(256, 4)
void gemm_sb_kern(const void* __restrict__ Av,
                  const __hip_bfloat16* __restrict__ Bt,
                  void* __restrict__ C, const float* __restrict__ bias,
                  int M, int N, int K, int mode)
{
  constexpr int ABYTES = AF32 ? 32768 : 16384;      // A tile: [128][64] f32 or bf16
  __shared__ __align__(16) char smc[ABYTES + 16384]; // + B tile [128][64] bf16

  const int t = threadIdx.x, lane = t & 63, w = t >> 6;
  const int wm = w >> 1, wn = w & 1;          // 2x2 waves, 64x64 out each
  const int lr = lane & 15, hi = lane >> 4;

  // XCD-aware bijective swizzle (gridDim.x % 8 == 0)
  int nwg = gridDim.x;
  int cpx = nwg >> 3;
  int swz = (blockIdx.x & 7) * cpx + (blockIdx.x >> 3);
  int nxt = N >> 7;
  int mt = swz / nxt, ntile = swz - mt * nxt;
  const long m0 = (long)mt * 128, n0 = (long)ntile * 128;

  f32x4 acc[4][4];
#pragma unroll
  for (int mi = 0; mi < 4; ++mi)
#pragma unroll
    for (int ni = 0; ni < 4; ++ni) acc[mi][ni] = {0.f, 0.f, 0.f, 0.f};

  const int NT = K >> 6;
  for (int kt = 0; kt < NT; ++kt) {
    __syncthreads();                       // prev tile's readers done
    // ---- stage A ----
    if constexpr (AF32) {
      const float* A = (const float*)Av;
      int row0 = t >> 4, slot = t & 15;    // [128][64] f32: 16 slots x 16B per row
      int eoff = (slot ^ row0) * 4;        // row&15 == row0 for all c
#pragma unroll
      for (int c = 0; c < 8; ++c) {
        int row = c * 16 + row0;
        gload_lds16(A + (m0 + row) * (long)K + kt * 64 + eoff,
                    (void*)(smc + c * 4096 + t * 16));
      }
    } else {
      const __hip_bfloat16* A = (const __hip_bfloat16*)Av;
      int row0 = t >> 3, slot = t & 7;     // [128][64] bf16: 8 slots x 16B per row
      int eoff = (slot ^ (row0 & 7)) * 8;
#pragma unroll
      for (int c = 0; c < 4; ++c) {
        int row = c * 32 + row0;
        gload_lds16(A + (m0 + row) * (long)K + kt * 64 + eoff,
                    (void*)(smc + c * 4096 + t * 16));
      }
    }
    // ---- stage B ----
    {
      int row0 = t >> 3, slot = t & 7;
      int eoff = (slot ^ (row0 & 7)) * 8;
#pragma unroll
      for (int c = 0; c < 4; ++c) {
        int row = c * 32 + row0;
        gload_lds16(Bt + (n0 + row) * (long)K + kt * 64 + eoff,
                    (void*)(smc + ABYTES + c * 4096 + t * 16));
      }
    }
    __syncthreads();                       // drains vmcnt: staged data visible

    // ---- fragments ----
    bf16x8 af[4][2], bfr[4][2];
#pragma unroll
    for (int mi = 0; mi < 4; ++mi) {
      int row = wm * 64 + mi * 16 + lr;    // row&15 == lr, row&7 == lr&7
#pragma unroll
      for (int kk = 0; kk < 2; ++kk) {
        if constexpr (AF32) {
          int s0 = 8 * kk + 2 * hi;
          f32x4 v0 = *reinterpret_cast<const f32x4*>(smc + row * 256 + (((s0)     ^ lr) << 4));
          f32x4 v1 = *reinterpret_cast<const f32x4*>(smc + row * 256 + (((s0 + 1) ^ lr) << 4));
          bf16x8 r;
#pragma unroll
          for (int e = 0; e < 4; ++e) {
            r[e]     = (short)__bfloat16_as_ushort(__float2bfloat16(v0[e]));
            r[e + 4] = (short)__bfloat16_as_ushort(__float2bfloat16(v1[e]));
          }
          af[mi][kk] = r;
        } else {
          af[mi][kk] = *reinterpret_cast<const bf16x8*>(
              smc + row * 128 + (((kk * 4 + hi) ^ (lr & 7)) << 4));
        }
      }
    }
#pragma unroll
    for (int ni = 0; ni < 4; ++ni) {
      int row = wn * 64 + ni * 16 + lr;
#pragma unroll
      for (int kk = 0; kk < 2; ++kk)
        bfr[ni][kk] = *reinterpret_cast<const bf16x8*>(
            smc + ABYTES + row * 128 + (((kk * 4 + hi) ^ (lr & 7)) << 4));
    }
#pragma unroll
    for (int mi = 0; mi < 4; ++mi)
#pragma unroll
      for (int ni = 0; ni < 4; ++ni) {
        acc[mi][ni] = __builtin_amdgcn_mfma_f32_16x16x32_bf16(af[mi][0], bfr[ni][0], acc[mi][ni], 0, 0, 0);
        acc[mi][ni] = __builtin_amdgcn_mfma_f32_16x16x32_bf16(af[mi][1], bfr[ni][1], acc[mi][ni], 0, 0, 0);
      }
  }

  // epilogue: direct stores (rows = wm*64+mi*16+hi*4+r, cols = wn*64+ni*16+lr)
  if (mode == 0) {
#pragma unroll
    for (int mi = 0; mi < 4; ++mi)
#pragma unroll
      for (int r = 0; r < 4; ++r) {
        long row = m0 + wm * 64 + mi * 16 + hi * 4 + r;
#pragma unroll
        for (int ni = 0; ni < 4; ++ni) {
          long col = n0 + wn * 64 + ni * 16 + lr;
          ((__hip_bfloat16*)C)[row * N + col] = __float2bfloat16(acc[mi][ni][r]);
        }
      }
  } else {
    float bv[4];
#pragma unroll
    for (int ni = 0; ni < 4; ++ni) bv[ni] = bias[n0 + wn * 64 + ni * 16 + lr];
#pragma unroll
    for (int mi = 0; mi < 4; ++mi)
#pragma unroll
      for (int r = 0; r < 4; ++r) {
        long row = m0 + wm * 64 + mi * 16 + hi * 4 + r;
#pragma unroll
        for (int ni = 0; ni < 4; ++ni) {
          long col = n0 + wn * 64 + ni * 16 + lr;
          ((float*)C)[row * N + col] = acc[mi][ni][r] + bv[ni];
        }
      }
  }
}

// ---------------- repack KV: kvc[616][2560] -> Kp[8][80][1280], Vt[8][20][64][96] ----------------
__global__ void repack_kv_kern(const __hip_bfloat16* __restrict__ kvc,
                               __hip_bfloat16* __restrict__ kp,
                               __hip_bfloat16* __restrict__ vt)
{
  int idx = blockIdx.x * 256 + threadIdx.x;
  const __hip_bfloat16 z = __float2bfloat16(0.f);
  if (idx < NB * NLP * ND) {
    int d = idx % ND;
    int l = (idx / ND) % NLP;
    int b = idx / (ND * NLP);
    kp[idx] = (l < NL) ? kvc[((long)(b * NL + l)) * 2560 + d] : z;
  }
  if (idx < NB * NH * NDH * NLPV) {
    int l  = idx % NLPV;
    int dh = (idx / NLPV) % NDH;
    int h  = (idx / (NLPV * NDH)) % NH;
    int b  = idx / (NLPV * NDH * NH);
    vt[idx] = (l < NL) ? kvc[((long)(b * NL + l)) * 2560 + ND + h * NDH + dh] : z;
  }
}

// ---------------- pass A: per-block max of scaled QK^T (256 s-rows/block) ----------------
__global__ __launch_bounds__(256)
void qk_max_kern(const __hip_bfloat16* __restrict__ qb,
                 const __hip_bfloat16* __restrict__ kp,
                 float* __restrict__ bmax)
{
  int t = threadIdx.x, lane = t & 63, wi = t >> 6;
  int b = blockIdx.z, h = blockIdx.y;
  int lr = lane & 15, lk = (lane >> 4) * 8;

  // hoist K fragments (reused across 4 s-subtiles)
  bf16x8 bk[5][2];
#pragma unroll
  for (int lt = 0; lt < 5; ++lt) {
    const __hip_bfloat16* Kr = kp + ((long)(b * NLP + lt * 16 + lr)) * ND + h * NDH + lk;
    bk[lt][0] = *reinterpret_cast<const bf16x8*>(Kr);
    bk[lt][1] = *reinterpret_cast<const bf16x8*>(Kr + 32);
  }

  float m = -1e30f;
#pragma unroll
  for (int st = 0; st < 4; ++st) {
    int s0 = blockIdx.x * 256 + wi * 64 + st * 16;
    const __hip_bfloat16* Qp = qb + ((long)(b * NS + s0 + lr)) * ND + h * NDH + lk;
    bf16x8 aq0 = *reinterpret_cast<const bf16x8*>(Qp);
    bf16x8 aq1 = *reinterpret_cast<const bf16x8*>(Qp + 32);
#pragma unroll
    for (int lt = 0; lt < 5; ++lt) {
      f32x4 sc = {0.f, 0.f, 0.f, 0.f};
      sc = __builtin_amdgcn_mfma_f32_16x16x32_bf16(aq0, bk[lt][0], sc, 0, 0, 0);
      sc = __builtin_amdgcn_mfma_f32_16x16x32_bf16(aq1, bk[lt][1], sc, 0, 0, 0);
      bool valid = (lt < 4) || (lr < 13);   // col l = lt*16 + (lane&15) < 77
      if (valid) {
#pragma unroll
        for (int r = 0; r < 4; ++r) m = fmaxf(m, sc[r]);
      }
    }
  }
#pragma unroll
  for (int k = 32; k >= 1; k >>= 1) m = fmaxf(m, __shfl_xor(m, k));

  __shared__ float wmx[4];
  if (lane == 0) wmx[wi] = m;
  __syncthreads();
  if (t == 0) {
    float mm = fmaxf(fmaxf(wmx[0], wmx[1]), fmaxf(wmx[2], wmx[3]));
    long bid = ((long)blockIdx.z * gridDim.y + blockIdx.y) * gridDim.x + blockIdx.x;
    bmax[bid] = mm * QK_SCALE;
  }
}

// ---------------- reduce block maxes -> bias coefficient ----------------
__global__ void reduce_max_kern(const float* __restrict__ bm, int n,
                                const float* __restrict__ sigma,
                                float* __restrict__ cb)
{
  __shared__ float sm[256];
  float m = -1e30f;
  for (int i = threadIdx.x; i < n; i += 256) m = fmaxf(m, bm[i]);
  sm[threadIdx.x] = m;
  __syncthreads();
  for (int s = 128; s > 0; s >>= 1) {
    if (threadIdx.x < (unsigned)s) sm[threadIdx.x] = fmaxf(sm[threadIdx.x], sm[threadIdx.x + s]);
    __syncthreads();
  }
  if (threadIdx.x == 0) cb[0] = log1pf(sigma[0] * 0.1f) * sm[0];
}

// ---------------- pass B: scores + bias + softmax + PV (256 s-rows/block) ----------------
__global__ __launch_bounds__(256)
void attn_kern(const __hip_bfloat16* __restrict__ qb,
               const __hip_bfloat16* __restrict__ kp,
               const __hip_bfloat16* __restrict__ vt,
               const float* __restrict__ rs,
               const float* __restrict__ cb,
               __hip_bfloat16* __restrict__ ao_out)
{
  __shared__ __align__(16) __hip_bfloat16 pl[4][16][NLPV];
  int t = threadIdx.x, lane = t & 63, wi = t >> 6;
  int b = blockIdx.z, h = blockIdx.y;
  int lr = lane & 15, hi = lane >> 4, lk = hi * 8;
  const float c = cb[0];

  // hoist K fragments
  bf16x8 bk[5][2];
#pragma unroll
  for (int lt = 0; lt < 5; ++lt) {
    const __hip_bfloat16* Kr = kp + ((long)(b * NLP + lt * 16 + lr)) * ND + h * NDH + lk;
    bk[lt][0] = *reinterpret_cast<const bf16x8*>(Kr);
    bk[lt][1] = *reinterpret_cast<const bf16x8*>(Kr + 32);
  }
  // zero PV pad cols 80..95 once (per-wave buffer)
#pragma unroll
  for (int r = 0; r < 4; ++r)
    pl[wi][hi * 4 + r][80 + lr] = __float2bfloat16(0.f);

  const __hip_bfloat16* Vb = vt + ((long)((b * NH + h) * NDH)) * NLPV;

#pragma unroll
  for (int st = 0; st < 4; ++st) {
    int s0 = blockIdx.x * 256 + wi * 64 + st * 16;
    const __hip_bfloat16* Qp = qb + ((long)(b * NS + s0 + lr)) * ND + h * NDH + lk;
    bf16x8 aq0 = *reinterpret_cast<const bf16x8*>(Qp);
    bf16x8 aq1 = *reinterpret_cast<const bf16x8*>(Qp + 32);

    f32x4 sc[5];
#pragma unroll
    for (int lt = 0; lt < 5; ++lt) {
      f32x4 z = {0.f, 0.f, 0.f, 0.f};
      z = __builtin_amdgcn_mfma_f32_16x16x32_bf16(aq0, bk[lt][0], z, 0, 0, 0);
      sc[lt] = __builtin_amdgcn_mfma_f32_16x16x32_bf16(aq1, bk[lt][1], z, 0, 0, 0);
    }

    float sv[5][4];
    float pm[4] = {-1e30f, -1e30f, -1e30f, -1e30f};
#pragma unroll
    for (int lt = 0; lt < 5; ++lt) {
      int l = lt * 16 + lr;
#pragma unroll
      for (int r = 0; r < 4; ++r) {
        if (l < NL) {
          int srow = s0 + hi * 4 + r;
          float v = sc[lt][r] * QK_SCALE + rs[((long)(b * NS + srow)) * NL + l] * c;
          sv[lt][r] = v;
          pm[r] = fmaxf(pm[r], v);
        } else {
          sv[lt][r] = -1e30f;
        }
      }
    }
#pragma unroll
    for (int r = 0; r < 4; ++r)
#pragma unroll
      for (int k = 8; k >= 1; k >>= 1) pm[r] = fmaxf(pm[r], __shfl_xor(pm[r], k));

    float p[5][4];
    float psum[4] = {0.f, 0.f, 0.f, 0.f};
#pragma unroll
    for (int lt = 0; lt < 5; ++lt) {
      int l = lt * 16 + lr;
#pragma unroll
      for (int r = 0; r < 4; ++r) {
        float e = (l < NL) ? __expf(sv[lt][r] - pm[r]) : 0.f;
        p[lt][r] = e;
        psum[r] += e;
      }
    }
#pragma unroll
    for (int r = 0; r < 4; ++r)
#pragma unroll
      for (int k = 8; k >= 1; k >>= 1) psum[r] += __shfl_xor(psum[r], k);
    float rinv[4];
#pragma unroll
    for (int r = 0; r < 4; ++r) rinv[r] = 1.f / psum[r];

    // fence (1): prior iteration's PV reads retired (WAR + TBAA-safe)
    LGKM0();

    // stage P (unnormalized) into per-wave LDS as PV's A-operand
#pragma unroll
    for (int lt = 0; lt < 5; ++lt)
#pragma unroll
      for (int r = 0; r < 4; ++r)
        pl[wi][hi * 4 + r][lt * 16 + lr] = __float2bfloat16(p[lt][r]);

    // fence (2): P-writes complete before PV reads issue (RAW-safe)
    LGKM0();

    f32x4 ao[4];
#pragma unroll
    for (int nt = 0; nt < 4; ++nt) ao[nt] = {0.f, 0.f, 0.f, 0.f};
#pragma unroll
    for (int ks = 0; ks < 3; ++ks) {
      bf16x8 pa = *reinterpret_cast<const bf16x8*>(&pl[wi][lr][ks * 32 + lk]);
#pragma unroll
      for (int nt = 0; nt < 4; ++nt) {
        bf16x8 bv = *reinterpret_cast<const bf16x8*>(Vb + ((long)(nt * 16 + lr)) * NLPV + ks * 32 + lk);
        ao[nt] = __builtin_amdgcn_mfma_f32_16x16x32_bf16(pa, bv, ao[nt], 0, 0, 0);
      }
    }

#pragma unroll
    for (int nt = 0; nt < 4; ++nt)
#pragma unroll
      for (int r = 0; r < 4; ++r) {
        int srow = s0 + hi * 4 + r;
        ao_out[((long)(b * NS + srow)) * ND + h * NDH + nt * 16 + lr] =
            __float2bfloat16(ao[nt][r] * rinv[r]);
      }
  }
}

// ---------------- launcher ----------------
extern "C" void kernel_launch(void* const* d_in, const int* in_sizes, int n_in,
                              void* d_out, int out_size, void* d_ws, size_t ws_size,
                              hipStream_t stream)
{
  const float* hs    = (const float*)d_in[0];
  const float* ehs   = (const float*)d_in[1];
  const float* rs    = (const float*)d_in[2];
  const float* Wq    = (const float*)d_in[3];
  const float* Wk    = (const float*)d_in[4];
  const float* Wv    = (const float*)d_in[5];
  const float* Wo    = (const float*)d_in[6];
  const float* bo    = (const float*)d_in[7];
  const float* sigma = (const float*)d_in[8];
  float* out = (float*)d_out;

  char* ws = (char*)d_ws;
  size_t off = 0;
  auto alloc = [&](size_t bytes) {
    void* p = ws + off;
    off = (off + bytes + 255) & ~(size_t)255;
    return p;
  };
  __hip_bfloat16* aob  = (__hip_bfloat16*)alloc((size_t)NB * NS * ND * 2);   // attn_out bf16
  __hip_bfloat16* qb   = (__hip_bfloat16*)alloc((size_t)NB * NS * ND * 2);
  __hip_bfloat16* wqt  = (__hip_bfloat16*)alloc((size_t)ND * ND * 2);
  __hip_bfloat16* wkvt = (__hip_bfloat16*)alloc((size_t)2560 * NC * 2);      // [Wk^T ; Wv^T]
  __hip_bfloat16* wot  = (__hip_bfloat16*)alloc((size_t)ND * ND * 2);
  __hip_bfloat16* ehsb = (__hip_bfloat16*)alloc((size_t)NB * NL * NC * 2);
  __hip_bfloat16* kvc  = (__hip_bfloat16*)alloc((size_t)NB * NL * 2560 * 2);
  __hip_bfloat16* kp   = (__hip_bfloat16*)alloc((size_t)NB * NLP * ND * 2);
  __hip_bfloat16* vt   = (__hip_bfloat16*)alloc((size_t)NB * NH * NDH * NLPV * 2);
  float* bmax = (float*)alloc(10240 * 4);
  float* cb   = (float*)alloc(256);

  // 1) encoder states to bf16 (hs conversion fused into Q-proj)
  cvt_bf16_kern<<<512, 256, 0, stream>>>(ehs, ehsb, (long)NB * NL * NC);

  // 2) weight transposes (f32 [K][N] -> bf16 [N][K])
  transpose_bf16_kern<<<dim3(40, 40), dim3(32, 8), 0, stream>>>(Wq, wqt, ND, ND);
  transpose_bf16_kern<<<dim3(40, 64), dim3(32, 8), 0, stream>>>(Wk, wkvt, NC, ND);
  transpose_bf16_kern<<<dim3(40, 64), dim3(32, 8), 0, stream>>>(Wv, wkvt + (size_t)ND * NC, NC, ND);
  transpose_bf16_kern<<<dim3(40, 40), dim3(32, 8), 0, stream>>>(Wo, wot, ND, ND);

  // 3) Q = hs @ Wq  (f32 A staged+converted in-kernel; bf16 out)
  gemm_sb_kern<true><<<2560, 256, 0, stream>>>(hs, wqt, qb, nullptr, NB * NS, ND, ND, 0);

  // 4) KV = ehs @ [Wk|Wv]  (bf16 out, compact [616][2560])
  gemm_bt_kern<<<dim3(5, 20), 256, 0, stream>>>(ehsb, wkvt, kvc, nullptr, NB * NL, 2560, NC, 0);

  // 5) repack K (padded rows) and V^T (padded cols)
  repack_kv_kern<<<3840, 256, 0, stream>>>(kvc, kp, vt);

  // 6) global max of scaled scores -> bias coefficient
  qk_max_kern<<<dim3(16, NH, NB), 256, 0, stream>>>(qb, kp, bmax);
  reduce_max_kern<<<1, 256, 0, stream>>>(bmax, 16 * NH * NB, sigma, cb);

  // 7) attention (recompute scores, +bias, softmax, PV) -> attn_out
  attn_kern<<<dim3(16, NH, NB), 256, 0, stream>>>(qb, kp, vt, rs, cb, aob);

  // 8) out = attn_out @ Wo + bo  (bf16 A; f32 out + bias)
  gemm_sb_kern<false><<<2560, 256, 0, stream>>>(aob, wot, out, bo, NB * NS, ND, ND, 1);
}

// Round 7
// 482.274 us; speedup vs baseline: 1.0969x; 1.0969x over previous
//
#include <hip/hip_runtime.h>
#include <hip/hip_bf16.h>
#include <math.h>

// Problem constants
#define NB 8
#define NS 4096
#define NL 77
#define NLP 80     // padded L for score tiles (5 x 16)
#define NLPV 96    // padded L for PV K-dim (3 x 32)
#define ND 1280
#define NC 2048
#define NH 20
#define NDH 64
#define QK_SCALE 0.125f

typedef __attribute__((ext_vector_type(4))) float f32x4;
typedef __attribute__((ext_vector_type(8))) short bf16x8;

static __device__ __forceinline__ void gload_lds16(const void* g, void* l) {
  __builtin_amdgcn_global_load_lds(
      (const __attribute__((address_space(1))) void*)g,
      (__attribute__((address_space(3))) void*)l, 16, 0, 0);
}

#define BAR() do { asm volatile("" ::: "memory"); __builtin_amdgcn_s_barrier(); asm volatile("" ::: "memory"); } while (0)
#define LGKM0() asm volatile("s_waitcnt lgkmcnt(0)" ::: "memory")

// ---------------- f32 -> bf16 convert ----------------
__global__ void cvt_bf16_kern(const float* __restrict__ in,
                              __hip_bfloat16* __restrict__ out, long n)
{
  long i = ((long)blockIdx.x * blockDim.x + threadIdx.x) * 4;
  long stride = (long)gridDim.x * blockDim.x * 4;
  for (; i < n; i += stride) {
    float4 v = *reinterpret_cast<const float4*>(in + i);
    union { __hip_bfloat16 h[4]; ushort4 u; } r;
    r.h[0] = __float2bfloat16(v.x);
    r.h[1] = __float2bfloat16(v.y);
    r.h[2] = __float2bfloat16(v.z);
    r.h[3] = __float2bfloat16(v.w);
    *reinterpret_cast<ushort4*>(out + i) = r.u;
  }
}

// ------------- transpose f32 [rows][cols] -> bf16 [cols][rows] -------------
__global__ void transpose_bf16_kern(const float* __restrict__ in,
                                    __hip_bfloat16* __restrict__ out,
                                    int rows, int cols)
{
  __shared__ float t[32][33];
  int c0 = blockIdx.x * 32, r0 = blockIdx.y * 32;
  int tx = threadIdx.x, ty = threadIdx.y;
  for (int i = ty; i < 32; i += 8) {
    int r = r0 + i, c = c0 + tx;
    t[i][tx] = (r < rows && c < cols) ? in[(long)r * cols + c] : 0.f;
  }
  __syncthreads();
  for (int i = ty; i < 32; i += 8) {
    int oc = c0 + i, orr = r0 + tx;   // out[oc][orr] = in[orr][oc]
    if (oc < cols && orr < rows)
      out[(long)oc * rows + orr] = __float2bfloat16(t[tx][i]);
  }
}

// ---------------- small GEMM (KV proj): C[M][N] = A @ Bt^T, m97-style ----------------
__global__ __launch_bounds__(256)
void gemm_bt_kern(const __hip_bfloat16* __restrict__ A,
                  const __hip_bfloat16* __restrict__ Bt,
                  void* __restrict__ C, const float* __restrict__ bias,
                  int M, int N, int K, int mode)
{
  __shared__ __align__(16) __hip_bfloat16 As[128 * 32];
  __shared__ __align__(16) __hip_bfloat16 Bs[128 * 32];
  const int t = threadIdx.x;
  const int lane = t & 63;
  const int w = t >> 6;
  const int wm = w >> 1, wn = w & 1;     // 2x2 waves of 64x64
  const int lr = lane & 15, hi = lane >> 4, lk = hi * 8;
  const long m0 = (long)blockIdx.x * 128;
  const long n0 = (long)blockIdx.y * 128;

  f32x4 acc[4][4];
#pragma unroll
  for (int mi = 0; mi < 4; ++mi)
#pragma unroll
    for (int ni = 0; ni < 4; ++ni) acc[mi][ni] = {0.f, 0.f, 0.f, 0.f};

  for (int k0 = 0; k0 < K; k0 += 32) {
    __syncthreads();
#pragma unroll
    for (int rnd = 0; rnd < 2; ++rnd) {
      int idx = rnd * 256 + t;
      int row = idx >> 2, kpp = (idx & 3) * 8;
      long arow = m0 + row; if (arow >= M) arow = M - 1;
      gload_lds16(A + arow * K + k0 + kpp, (void*)(As + idx * 8));
      long brow = n0 + row;
      gload_lds16(Bt + brow * K + k0 + kpp, (void*)(Bs + idx * 8));
    }
    __syncthreads();

    bf16x8 af[4], bfr[4];
#pragma unroll
    for (int i = 0; i < 4; ++i) {
      af[i]  = *reinterpret_cast<const bf16x8*>(As + (wm * 64 + i * 16 + lr) * 32 + lk);
      bfr[i] = *reinterpret_cast<const bf16x8*>(Bs + (wn * 64 + i * 16 + lr) * 32 + lk);
    }
#pragma unroll
    for (int mi = 0; mi < 4; ++mi)
#pragma unroll
      for (int ni = 0; ni < 4; ++ni)
        acc[mi][ni] = __builtin_amdgcn_mfma_f32_16x16x32_bf16(af[mi], bfr[ni], acc[mi][ni], 0, 0, 0);
  }

#pragma unroll
  for (int mi = 0; mi < 4; ++mi) {
#pragma unroll
    for (int r = 0; r < 4; ++r) {
      long row = m0 + wm * 64 + mi * 16 + hi * 4 + r;
      if (row < M) {
#pragma unroll
        for (int ni = 0; ni < 4; ++ni) {
          long col = n0 + wn * 64 + ni * 16 + lr;
          if (mode == 0)
            ((__hip_bfloat16*)C)[row * N + col] = __float2bfloat16(acc[mi][ni][r]);
          else
            ((float*)C)[row * N + col] = acc[mi][ni][r] + bias[col];
        }
      }
    }
  }
}

// ---- big GEMM: 128x128 tile, BK=64, 4 waves, 64KB dbuf LDS, stage-early + counted vmcnt ----
// MODE 0: C bf16. MODE 1: C f32 + bias. MODE 2: C bf16 + fused QK^T score-max -> bmax[block].
// Requires M%128==0, N%128==0, K%64==0, K/64>=3, gridDim.x == (M/128)*(N/128), grid%8==0.
template<int MODE>
__global__ __launch_bounds__(256, 2)
void gemm128_kern(const __hip_bfloat16* __restrict__ A,
                  const __hip_bfloat16* __restrict__ Bt,
                  void* __restrict__ C, const float* __restrict__ bias,
                  const __hip_bfloat16* __restrict__ kp,
                  float* __restrict__ bmax,
                  int M, int N, int K)
{
  // LDS bytes: A bufs: [0,32768) (2 x 16384), B bufs: [32768,65536)
  __shared__ __align__(16) __hip_bfloat16 sm[32768];   // 64 KiB
  char* smc = (char*)sm;

  const int t = threadIdx.x, lane = t & 63, w = t >> 6;
  const int wm = w >> 1, wn = w & 1;          // 2 x 2 waves, 64x64 out each
  const int lr = lane & 15, hi = lane >> 4;
  const int sw = lr & 7;

  // XCD-aware bijective swizzle (gridDim.x % 8 == 0)
  int nwg = gridDim.x;
  int cpx = nwg >> 3;
  int swz = (blockIdx.x & 7) * cpx + (blockIdx.x >> 3);
  int nxt = N >> 7;
  int mt = swz / nxt, ntile = swz - mt * nxt;
  const long m0 = (long)mt * 128, n0 = (long)ntile * 128;

  // staging: row = c*32 + (t>>3), slot = t&7 ; 16B per load
  const int srow  = t >> 3;
  const int skoff = ((t & 7) ^ (srow & 7)) * 8;   // pre-swizzled source k-offset (elems)
  const int sdst  = t * 16;                        // + c*4096 bytes

  f32x4 acc[4][4];
#pragma unroll
  for (int mi = 0; mi < 4; ++mi)
#pragma unroll
    for (int ni = 0; ni < 4; ++ni) acc[mi][ni] = {0.f, 0.f, 0.f, 0.f};

  auto stageA = [&](int b, int kt) {
#pragma unroll
    for (int c = 0; c < 4; ++c)
      gload_lds16(A + (m0 + c * 32 + srow) * (long)K + kt * 64 + skoff,
                  (void*)(smc + b * 16384 + c * 4096 + sdst));
  };
  auto stageB = [&](int b, int kt) {
#pragma unroll
    for (int c = 0; c < 4; ++c)
      gload_lds16(Bt + (n0 + c * 32 + srow) * (long)K + kt * 64 + skoff,
                  (void*)(smc + 32768 + b * 16384 + c * 4096 + sdst));
  };

  const int NT = K >> 6;
  // prologue: stage tile0 -> buf0, tile1 -> buf1 (8 loads/thread each)
  stageA(0, 0); stageB(0, 0);
  stageA(1, 1); stageB(1, 1);
  asm volatile("s_waitcnt vmcnt(8)" ::: "memory");   // tile 0 resident; tile 1 in flight
  BAR();

  for (int t2 = 0; t2 < NT; ++t2) {
    const int b = t2 & 1;
    const char* pa = smc + b * 16384;
    const char* pb = smc + 32768 + b * 16384;
    const bool pf = (t2 + 2 < NT);

    bf16x8 af[4][2], bfr[4][2];
#pragma unroll
    for (int mi = 0; mi < 4; ++mi) {
      int row = wm * 64 + mi * 16 + lr;
#pragma unroll
      for (int kk = 0; kk < 2; ++kk)
        af[mi][kk] = *reinterpret_cast<const bf16x8*>(
            pa + row * 128 + ((((kk * 4 + hi) ^ sw)) << 4));
    }
#pragma unroll
    for (int ni = 0; ni < 4; ++ni) {
      int row = wn * 64 + ni * 16 + lr;
#pragma unroll
      for (int kk = 0; kk < 2; ++kk)
        bfr[ni][kk] = *reinterpret_cast<const bf16x8*>(
            pb + row * 128 + ((((kk * 4 + hi) ^ sw)) << 4));
    }
    // all reads of buf b retired block-wide, then issue next-next tile's staging EARLY
    LGKM0();
    BAR();
    if (pf) { stageA(b, t2 + 2); stageB(b, t2 + 2); }

    __builtin_amdgcn_s_setprio(1);
#pragma unroll
    for (int mi = 0; mi < 4; ++mi)
#pragma unroll
      for (int ni = 0; ni < 4; ++ni) {
        acc[mi][ni] = __builtin_amdgcn_mfma_f32_16x16x32_bf16(af[mi][0], bfr[ni][0], acc[mi][ni], 0, 0, 0);
        acc[mi][ni] = __builtin_amdgcn_mfma_f32_16x16x32_bf16(af[mi][1], bfr[ni][1], acc[mi][ni], 0, 0, 0);
      }
    __builtin_amdgcn_s_setprio(0);

    if (pf) { asm volatile("s_waitcnt vmcnt(8)" ::: "memory"); }   // tile t2+1 resident
    else    { asm volatile("s_waitcnt vmcnt(0)" ::: "memory"); }
    BAR();
  }

  // ---------------- epilogue ----------------
  if constexpr (MODE == 1) {
    float bv[4];
#pragma unroll
    for (int ni = 0; ni < 4; ++ni) bv[ni] = bias[n0 + wn * 64 + ni * 16 + lr];
#pragma unroll
    for (int mi = 0; mi < 4; ++mi)
#pragma unroll
      for (int r = 0; r < 4; ++r) {
        long row = m0 + wm * 64 + mi * 16 + hi * 4 + r;
#pragma unroll
        for (int ni = 0; ni < 4; ++ni) {
          long col = n0 + wn * 64 + ni * 16 + lr;
          ((float*)C)[row * N + col] = acc[mi][ni][r] + bv[ni];
        }
      }
  } else {
    // bf16 store (+ optional LDS staging for fused QK max)
    __hip_bfloat16* qsl = (__hip_bfloat16*)smc;   // [128][128], 16B-block XOR swizzle
#pragma unroll
    for (int mi = 0; mi < 4; ++mi)
#pragma unroll
      for (int r = 0; r < 4; ++r) {
        int rowl = wm * 64 + mi * 16 + hi * 4 + r;
        long row = m0 + rowl;
#pragma unroll
        for (int ni = 0; ni < 4; ++ni) {
          int col = wn * 64 + ni * 16 + lr;
          __hip_bfloat16 v = __float2bfloat16(acc[mi][ni][r]);
          ((__hip_bfloat16*)C)[row * N + n0 + col] = v;
          if constexpr (MODE == 2) {
            int bw = (col >> 3) ^ (rowl & 7);
            qsl[rowl * 128 + (bw << 3) + (col & 7)] = v;
          }
        }
      }
    if constexpr (MODE == 2) {
      LGKM0();
      BAR();
      const int bb = (int)(m0 >> 12);             // batch index (NS=4096 rows per batch)
      float mx = -1e30f;
#pragma unroll
      for (int hh = 0; hh < 2; ++hh) {
        const int h = (int)(n0 >> 6) + hh;        // two complete heads per 128-col tile
        bf16x8 bk0[5], bk1[5];
#pragma unroll
        for (int lt = 0; lt < 5; ++lt) {
          const __hip_bfloat16* Kr = kp + ((long)(bb * NLP + lt * 16 + lr)) * ND + h * NDH + hi * 8;
          bk0[lt] = *reinterpret_cast<const bf16x8*>(Kr);
          bk1[lt] = *reinterpret_cast<const bf16x8*>(Kr + 32);
        }
#pragma unroll
        for (int su = 0; su < 2; ++su) {
          int qrow = (w * 2 + su) * 16 + lr;      // qrow&7 == lr&7
          int bi0 = (hh * 8 + hi)     ^ sw;
          int bi1 = (hh * 8 + 4 + hi) ^ sw;
          bf16x8 aq0 = *reinterpret_cast<const bf16x8*>(qsl + qrow * 128 + (bi0 << 3));
          bf16x8 aq1 = *reinterpret_cast<const bf16x8*>(qsl + qrow * 128 + (bi1 << 3));
#pragma unroll
          for (int lt = 0; lt < 5; ++lt) {
            f32x4 sc = {0.f, 0.f, 0.f, 0.f};
            sc = __builtin_amdgcn_mfma_f32_16x16x32_bf16(aq0, bk0[lt], sc, 0, 0, 0);
            sc = __builtin_amdgcn_mfma_f32_16x16x32_bf16(aq1, bk1[lt], sc, 0, 0, 0);
            if ((lt < 4) || (lr < 13)) {          // col l = lt*16 + lr < 77
#pragma unroll
              for (int r = 0; r < 4; ++r) mx = fmaxf(mx, sc[r]);
            }
          }
        }
      }
#pragma unroll
      for (int k = 32; k >= 1; k >>= 1) mx = fmaxf(mx, __shfl_xor(mx, k));
      float* wmx = (float*)(smc + 32768);
      if (lane == 0) wmx[w] = mx;
      LGKM0();
      BAR();
      if (t == 0) {
        float mm = fmaxf(fmaxf(wmx[0], wmx[1]), fmaxf(wmx[2], wmx[3]));
        bmax[blockIdx.x] = mm * QK_SCALE;
      }
    }
  }
}

// ---------------- repack KV: kvc[616][2560] -> Kp[8][80][1280], Vt[8][20][64][96] ----------------
__global__ void repack_kv_kern(const __hip_bfloat16* __restrict__ kvc,
                               __hip_bfloat16* __restrict__ kp,
                               __hip_bfloat16* __restrict__ vt)
{
  int idx = blockIdx.x * 256 + threadIdx.x;
  const __hip_bfloat16 z = __float2bfloat16(0.f);
  if (idx < NB * NLP * ND) {
    int d = idx % ND;
    int l = (idx / ND) % NLP;
    int b = idx / (ND * NLP);
    kp[idx] = (l < NL) ? kvc[((long)(b * NL + l)) * 2560 + d] : z;
  }
  if (idx < NB * NH * NDH * NLPV) {
    int l  = idx % NLPV;
    int dh = (idx / NLPV) % NDH;
    int h  = (idx / (NLPV * NDH)) % NH;
    int b  = idx / (NLPV * NDH * NH);
    vt[idx] = (l < NL) ? kvc[((long)(b * NL + l)) * 2560 + ND + h * NDH + dh] : z;
  }
}

// ---------------- reduce block maxes -> bias coefficient ----------------
__global__ void reduce_max_kern(const float* __restrict__ bm, int n,
                                const float* __restrict__ sigma,
                                float* __restrict__ cb)
{
  __shared__ float sm[256];
  float m = -1e30f;
  for (int i = threadIdx.x; i < n; i += 256) m = fmaxf(m, bm[i]);
  sm[threadIdx.x] = m;
  __syncthreads();
  for (int s = 128; s > 0; s >>= 1) {
    if (threadIdx.x < (unsigned)s) sm[threadIdx.x] = fmaxf(sm[threadIdx.x], sm[threadIdx.x + s]);
    __syncthreads();
  }
  if (threadIdx.x == 0) cb[0] = log1pf(sigma[0] * 0.1f) * sm[0];
}

// ---------------- pass B: scores + bias + softmax + PV (256 s-rows/block) ----------------
__global__ __launch_bounds__(256)
void attn_kern(const __hip_bfloat16* __restrict__ qb,
               const __hip_bfloat16* __restrict__ kp,
               const __hip_bfloat16* __restrict__ vt,
               const float* __restrict__ rs,
               const float* __restrict__ cb,
               __hip_bfloat16* __restrict__ ao_out)
{
  __shared__ __align__(16) __hip_bfloat16 pl[4][16][NLPV];
  int t = threadIdx.x, lane = t & 63, wi = t >> 6;
  int b = blockIdx.z, h = blockIdx.y;
  int lr = lane & 15, hi = lane >> 4, lk = hi * 8;
  const float c = cb[0];

  // hoist K fragments
  bf16x8 bk[5][2];
#pragma unroll
  for (int lt = 0; lt < 5; ++lt) {
    const __hip_bfloat16* Kr = kp + ((long)(b * NLP + lt * 16 + lr)) * ND + h * NDH + lk;
    bk[lt][0] = *reinterpret_cast<const bf16x8*>(Kr);
    bk[lt][1] = *reinterpret_cast<const bf16x8*>(Kr + 32);
  }
  // zero PV pad cols 80..95 once (per-wave buffer)
#pragma unroll
  for (int r = 0; r < 4; ++r)
    pl[wi][hi * 4 + r][80 + lr] = __float2bfloat16(0.f);

  const __hip_bfloat16* Vb = vt + ((long)((b * NH + h) * NDH)) * NLPV;

#pragma unroll
  for (int st = 0; st < 4; ++st) {
    int s0 = blockIdx.x * 256 + wi * 64 + st * 16;
    const __hip_bfloat16* Qp = qb + ((long)(b * NS + s0 + lr)) * ND + h * NDH + lk;
    bf16x8 aq0 = *reinterpret_cast<const bf16x8*>(Qp);
    bf16x8 aq1 = *reinterpret_cast<const bf16x8*>(Qp + 32);

    f32x4 sc[5];
#pragma unroll
    for (int lt = 0; lt < 5; ++lt) {
      f32x4 z = {0.f, 0.f, 0.f, 0.f};
      z = __builtin_amdgcn_mfma_f32_16x16x32_bf16(aq0, bk[lt][0], z, 0, 0, 0);
      sc[lt] = __builtin_amdgcn_mfma_f32_16x16x32_bf16(aq1, bk[lt][1], z, 0, 0, 0);
    }

    float sv[5][4];
    float pm[4] = {-1e30f, -1e30f, -1e30f, -1e30f};
#pragma unroll
    for (int lt = 0; lt < 5; ++lt) {
      int l = lt * 16 + lr;
#pragma unroll
      for (int r = 0; r < 4; ++r) {
        if (l < NL) {
          int srow = s0 + hi * 4 + r;
          float v = sc[lt][r] * QK_SCALE + rs[((long)(b * NS + srow)) * NL + l] * c;
          sv[lt][r] = v;
          pm[r] = fmaxf(pm[r], v);
        } else {
          sv[lt][r] = -1e30f;
        }
      }
    }
#pragma unroll
    for (int r = 0; r < 4; ++r)
#pragma unroll
      for (int k = 8; k >= 1; k >>= 1) pm[r] = fmaxf(pm[r], __shfl_xor(pm[r], k));

    float p[5][4];
    float psum[4] = {0.f, 0.f, 0.f, 0.f};
#pragma unroll
    for (int lt = 0; lt < 5; ++lt) {
      int l = lt * 16 + lr;
#pragma unroll
      for (int r = 0; r < 4; ++r) {
        float e = (l < NL) ? __expf(sv[lt][r] - pm[r]) : 0.f;
        p[lt][r] = e;
        psum[r] += e;
      }
    }
#pragma unroll
    for (int r = 0; r < 4; ++r)
#pragma unroll
      for (int k = 8; k >= 1; k >>= 1) psum[r] += __shfl_xor(psum[r], k);
    float rinv[4];
#pragma unroll
    for (int r = 0; r < 4; ++r) rinv[r] = 1.f / psum[r];

    // fence (1): prior iteration's PV reads retired (WAR + TBAA-safe)
    LGKM0();

    // stage P (unnormalized) into per-wave LDS as PV's A-operand
#pragma unroll
    for (int lt = 0; lt < 5; ++lt)
#pragma unroll
      for (int r = 0; r < 4; ++r)
        pl[wi][hi * 4 + r][lt * 16 + lr] = __float2bfloat16(p[lt][r]);

    // fence (2): P-writes complete before PV reads issue (RAW-safe)
    LGKM0();

    f32x4 ao[4];
#pragma unroll
    for (int nt = 0; nt < 4; ++nt) ao[nt] = {0.f, 0.f, 0.f, 0.f};
#pragma unroll
    for (int ks = 0; ks < 3; ++ks) {
      bf16x8 pa = *reinterpret_cast<const bf16x8*>(&pl[wi][lr][ks * 32 + lk]);
#pragma unroll
      for (int nt = 0; nt < 4; ++nt) {
        bf16x8 bv = *reinterpret_cast<const bf16x8*>(Vb + ((long)(nt * 16 + lr)) * NLPV + ks * 32 + lk);
        ao[nt] = __builtin_amdgcn_mfma_f32_16x16x32_bf16(pa, bv, ao[nt], 0, 0, 0);
      }
    }

#pragma unroll
    for (int nt = 0; nt < 4; ++nt)
#pragma unroll
      for (int r = 0; r < 4; ++r) {
        int srow = s0 + hi * 4 + r;
        ao_out[((long)(b * NS + srow)) * ND + h * NDH + nt * 16 + lr] =
            __float2bfloat16(ao[nt][r] * rinv[r]);
      }
  }
}

// ---------------- launcher ----------------
extern "C" void kernel_launch(void* const* d_in, const int* in_sizes, int n_in,
                              void* d_out, int out_size, void* d_ws, size_t ws_size,
                              hipStream_t stream)
{
  const float* hs    = (const float*)d_in[0];
  const float* ehs   = (const float*)d_in[1];
  const float* rs    = (const float*)d_in[2];
  const float* Wq    = (const float*)d_in[3];
  const float* Wk    = (const float*)d_in[4];
  const float* Wv    = (const float*)d_in[5];
  const float* Wo    = (const float*)d_in[6];
  const float* bo    = (const float*)d_in[7];
  const float* sigma = (const float*)d_in[8];
  float* out = (float*)d_out;

  char* ws = (char*)d_ws;
  size_t off = 0;
  auto alloc = [&](size_t bytes) {
    void* p = ws + off;
    off = (off + bytes + 255) & ~(size_t)255;
    return p;
  };
  __hip_bfloat16* hsb  = (__hip_bfloat16*)alloc((size_t)NB * NS * ND * 2);   // hs bf16; reused as attn_out
  __hip_bfloat16* qb   = (__hip_bfloat16*)alloc((size_t)NB * NS * ND * 2);
  __hip_bfloat16* wqt  = (__hip_bfloat16*)alloc((size_t)ND * ND * 2);
  __hip_bfloat16* wkvt = (__hip_bfloat16*)alloc((size_t)2560 * NC * 2);      // [Wk^T ; Wv^T]
  __hip_bfloat16* wot  = (__hip_bfloat16*)alloc((size_t)ND * ND * 2);
  __hip_bfloat16* ehsb = (__hip_bfloat16*)alloc((size_t)NB * NL * NC * 2);
  __hip_bfloat16* kvc  = (__hip_bfloat16*)alloc((size_t)NB * NL * 2560 * 2);
  __hip_bfloat16* kp   = (__hip_bfloat16*)alloc((size_t)NB * NLP * ND * 2);
  __hip_bfloat16* vt   = (__hip_bfloat16*)alloc((size_t)NB * NH * NDH * NLPV * 2);
  float* bmax = (float*)alloc(10240 * 4);
  float* cb   = (float*)alloc(256);

  // 1) dtype conversions
  cvt_bf16_kern<<<2048, 256, 0, stream>>>(hs, hsb, (long)NB * NS * ND);
  cvt_bf16_kern<<<512, 256, 0, stream>>>(ehs, ehsb, (long)NB * NL * NC);

  // 2) weight transposes (f32 [K][N] -> bf16 [N][K])
  transpose_bf16_kern<<<dim3(40, 40), dim3(32, 8), 0, stream>>>(Wq, wqt, ND, ND);
  transpose_bf16_kern<<<dim3(40, 64), dim3(32, 8), 0, stream>>>(Wk, wkvt, NC, ND);
  transpose_bf16_kern<<<dim3(40, 64), dim3(32, 8), 0, stream>>>(Wv, wkvt + (size_t)ND * NC, NC, ND);
  transpose_bf16_kern<<<dim3(40, 40), dim3(32, 8), 0, stream>>>(Wo, wot, ND, ND);

  // 3) KV = ehs @ [Wk|Wv] + repack (Q-proj's fused score-max needs kp ready)
  gemm_bt_kern<<<dim3(5, 20), 256, 0, stream>>>(ehsb, wkvt, kvc, nullptr, NB * NL, 2560, NC, 0);
  repack_kv_kern<<<3840, 256, 0, stream>>>(kvc, kp, vt);

  // 4) Q = hs @ Wq (bf16 out) + fused global score-max per block
  gemm128_kern<2><<<2560, 256, 0, stream>>>(hsb, wqt, qb, nullptr, kp, bmax, NB * NS, ND, ND);

  // 5) reduce block maxes -> bias coefficient
  reduce_max_kern<<<1, 256, 0, stream>>>(bmax, 2560, sigma, cb);

  // 6) attention (recompute scores, +bias, softmax, PV) -> attn_out (reuses hsb)
  attn_kern<<<dim3(16, NH, NB), 256, 0, stream>>>(qb, kp, vt, rs, cb, hsb);

  // 7) out = attn_out @ Wo + bo  (f32 out)
  gemm128_kern<1><<<2560, 256, 0, stream>>>(hsb, wot, out, bo, nullptr, nullptr, NB * NS, ND, ND);
}